// Round 2
// baseline (101.173 us; speedup 1.0000x reference)
//
#include <hip/hip_runtime.h>
#include <hip/hip_fp16.h>

#define NN 2048

typedef _Float16 f16x8 __attribute__((ext_vector_type(8)));
typedef float f32x16 __attribute__((ext_vector_type(16)));

// ---------------------------------------------------------------------------
// Prep: proj = A@Wp.T + bp  (2048x32), then
//       pa'  = proj@Wa.T + b1  (f16, b1 folded),  pb = proj@Wb.T (f16)
// Wa = W1[:, :32], Wb = W1[:, 32:]
// Block = 256 threads = 8 rows x 32 k.
// ---------------------------------------------------------------------------
__global__ __launch_bounds__(256) void prep_kernel(
    const float* __restrict__ A, const float* __restrict__ Wp,
    const float* __restrict__ bp, const float* __restrict__ W1,
    const float* __restrict__ b1,
    _Float16* __restrict__ pa, _Float16* __restrict__ pb)
{
    __shared__ float projLDS[8][32];
    const int t = threadIdx.x;
    const int rl = t >> 5;        // local row 0..7
    const int k  = t & 31;        // output unit 0..31
    const int row = blockIdx.x * 8 + rl;

    const float4* xa = (const float4*)(A + row * 64);
    const float4* wp = (const float4*)(Wp + k * 64);
    float acc = bp[k];
#pragma unroll
    for (int m = 0; m < 16; ++m) {
        float4 xv = xa[m], wv = wp[m];
        acc += xv.x * wv.x + xv.y * wv.y + xv.z * wv.z + xv.w * wv.w;
    }
    projLDS[rl][k] = acc;
    __syncthreads();

    const float4* w1a = (const float4*)(W1 + k * 64);        // m = 0..31
    const float4* w1b = (const float4*)(W1 + k * 64 + 32);   // m = 32..63
    const float4* pr  = (const float4*)(projLDS[rl]);
    float sa = b1[k], sb = 0.f;
#pragma unroll
    for (int m = 0; m < 8; ++m) {
        float4 p = pr[m], wa = w1a[m], wb = w1b[m];
        sa += p.x * wa.x + p.y * wa.y + p.z * wa.z + p.w * wa.w;
        sb += p.x * wb.x + p.y * wb.y + p.z * wb.z + p.w * wb.w;
    }
    pa[row * 32 + k] = (_Float16)sa;
    pb[row * 32 + k] = (_Float16)sb;
}

// ---------------------------------------------------------------------------
// Main: one wave computes a 32i x 32j output tile.
// Per i: D[h][pair] = W2(A, 32x16 rows, padded) . h1^T(B, 16x32 pairs)
// via two mfma_f32_32x32x16_f16 (k-halves 0..15 and 16..31), C preloaded
// with b2. Epilogue: per-lane 8x relu*W3 fma, shfl_xor(32), sigmoid.
// D layout (verified m74/m101): col = lane&31, row = (r&3)+8*(r>>2)+4*(lane>>5).
// A/B per-lane k-permutation is irrelevant as long as both fragments use
// the same (group,j)->k map (contraction-index consistency).
// ---------------------------------------------------------------------------
__global__ __launch_bounds__(256) void sim_kernel(
    const _Float16* __restrict__ pa, const _Float16* __restrict__ pb,
    const float* __restrict__ W2, const float* __restrict__ b2,
    const float* __restrict__ W3, const float* __restrict__ b3,
    float* __restrict__ out)
{
    const int lane = threadIdx.x & 63;
    const int gwid = blockIdx.x * 4 + (threadIdx.x >> 6);  // 0..4095
    const int i0 = (gwid >> 6) * 32;   // 64 i-tiles
    const int jb = (gwid & 63) * 32;   // 64 j-tiles
    const int p  = lane & 31;          // pair column within tile
    const int g  = lane >> 5;          // k-group half (0/1)

    // persistent pb fragment for this wave's 32 j's
    const _Float16* pbrow = pb + (size_t)(jb + p) * 32;
    f16x8 pblo = *(const f16x8*)(pbrow + g * 8);        // k = g*8 + jj
    f16x8 pbhi = *(const f16x8*)(pbrow + 16 + g * 8);   // k = 16 + g*8 + jj

    // W2 as A-operand: A[m][k], m = lane&31 (rows >= 16 zero-padded)
    f16x8 w2lo = {};
    f16x8 w2hi = {};
    if (p < 16) {
        const float* w2r = W2 + p * 32;
#pragma unroll
        for (int jj = 0; jj < 8; ++jj) {
            w2lo[jj] = (_Float16)w2r[g * 8 + jj];
            w2hi[jj] = (_Float16)w2r[16 + g * 8 + jj];
        }
    }

    // per-lane W3 and b2(C-init) following the D row map
    float w3r[8];
    f32x16 cinit;
#pragma unroll
    for (int r = 0; r < 4; ++r) {
        w3r[r]     = W3[4 * g + r];
        w3r[4 + r] = W3[8 + 4 * g + r];
        cinit[r]     = b2[4 * g + r];
        cinit[4 + r] = b2[8 + 4 * g + r];
    }
#pragma unroll
    for (int r = 8; r < 16; ++r) cinit[r] = 0.f;

    const float b3v = b3[0];
    const f16x8 zero = {};
    const int j = jb + p;

    for (int ii = 0; ii < 32; ++ii) {
        const int i = i0 + ii;
        const _Float16* parow = pa + (size_t)i * 32;
        f16x8 alo = *(const f16x8*)(parow + g * 8);
        f16x8 ahi = *(const f16x8*)(parow + 16 + g * 8);
        f16x8 h1lo = __builtin_elementwise_max(alo + pblo, zero);  // relu(pa'+pb)
        f16x8 h1hi = __builtin_elementwise_max(ahi + pbhi, zero);

        f32x16 d = __builtin_amdgcn_mfma_f32_32x32x16_f16(w2lo, h1lo, cinit, 0, 0, 0);
        d        = __builtin_amdgcn_mfma_f32_32x32x16_f16(w2hi, h1hi, d,     0, 0, 0);

        // second layer: logit = sum_h relu(h2[h]) * W3[h] + b3
        float partial = 0.f;
#pragma unroll
        for (int r = 0; r < 8; ++r)
            partial = fmaf(fmaxf(d[r], 0.f), w3r[r], partial);
        partial += __shfl_xor(partial, 32, 64);
        const float z = partial + b3v;
        float sim = __builtin_amdgcn_rcpf(1.f + __expf(-z));
        if (i == j) sim = 1.f;
        if (lane < 32) out[(size_t)i * NN + j] = sim;
    }
}

extern "C" void kernel_launch(void* const* d_in, const int* in_sizes, int n_in,
                              void* d_out, int out_size, void* d_ws, size_t ws_size,
                              hipStream_t stream)
{
    const float* A  = (const float*)d_in[0];
    const float* Wp = (const float*)d_in[1];
    const float* bp = (const float*)d_in[2];
    const float* W1 = (const float*)d_in[3];
    const float* b1 = (const float*)d_in[4];
    const float* W2 = (const float*)d_in[5];
    const float* b2 = (const float*)d_in[6];
    const float* W3 = (const float*)d_in[7];
    const float* b3 = (const float*)d_in[8];
    float* out = (float*)d_out;

    _Float16* pa = (_Float16*)d_ws;        // 2048*32 f16 = 128 KB
    _Float16* pb = pa + NN * 32;           // next 128 KB

    prep_kernel<<<NN / 8, 256, 0, stream>>>(A, Wp, bp, W1, b1, pa, pb);
    sim_kernel<<<1024, 256, 0, stream>>>(pa, pb, W2, b2, W3, b3, out);
}

// Round 3
// 98.996 us; speedup vs baseline: 1.0220x; 1.0220x over previous
//
#include <hip/hip_runtime.h>
#include <hip/hip_fp16.h>

#define NN 2048

typedef _Float16 f16x8 __attribute__((ext_vector_type(8)));
typedef float f32x16 __attribute__((ext_vector_type(16)));

// ---------------------------------------------------------------------------
// Prep: proj = A@Wp.T + bp  (2048x32), then
//       pa'  = proj@Wa.T + b1  (f16, b1 folded),  pb = proj@Wb.T (f16)
// Wa = W1[:, :32], Wb = W1[:, 32:]
// Block = 256 threads = 8 rows x 32 k.
// ---------------------------------------------------------------------------
__global__ __launch_bounds__(256) void prep_kernel(
    const float* __restrict__ A, const float* __restrict__ Wp,
    const float* __restrict__ bp, const float* __restrict__ W1,
    const float* __restrict__ b1,
    _Float16* __restrict__ pa, _Float16* __restrict__ pb)
{
    __shared__ float projLDS[8][32];
    const int t = threadIdx.x;
    const int rl = t >> 5;        // local row 0..7
    const int k  = t & 31;        // output unit 0..31
    const int row = blockIdx.x * 8 + rl;

    const float4* xa = (const float4*)(A + row * 64);
    const float4* wp = (const float4*)(Wp + k * 64);
    float acc = bp[k];
#pragma unroll
    for (int m = 0; m < 16; ++m) {
        float4 xv = xa[m], wv = wp[m];
        acc += xv.x * wv.x + xv.y * wv.y + xv.z * wv.z + xv.w * wv.w;
    }
    projLDS[rl][k] = acc;
    __syncthreads();

    const float4* w1a = (const float4*)(W1 + k * 64);        // m = 0..31
    const float4* w1b = (const float4*)(W1 + k * 64 + 32);   // m = 32..63
    const float4* pr  = (const float4*)(projLDS[rl]);
    float sa = b1[k], sb = 0.f;
#pragma unroll
    for (int m = 0; m < 8; ++m) {
        float4 p = pr[m], wa = w1a[m], wb = w1b[m];
        sa += p.x * wa.x + p.y * wa.y + p.z * wa.z + p.w * wa.w;
        sb += p.x * wb.x + p.y * wb.y + p.z * wb.z + p.w * wb.w;
    }
    pa[row * 32 + k] = (_Float16)sa;
    pb[row * 32 + k] = (_Float16)sb;
}

// ---------------------------------------------------------------------------
// Main: one wave computes a 32i x 32j output tile; 4 waves/block share i0.
// pa i-tile (32x32 f16 = 2KB) staged in LDS once per block; per-iteration
// reads are broadcast ds_read_b128 (no vmem in the hot loop).
// Per i: D[h][pair] = W2(A, 32x16 rows, padded) . h1^T(B, 16x32 pairs)
// via two mfma_f32_32x32x16_f16 (k-halves), C preloaded with b2.
// D layout (verified m74/m101): col = lane&31, row = (r&3)+8*(r>>2)+4*(lane>>5).
// A/B per-lane k-permutation cancels (same (g,elem)->k map on both operands).
// ---------------------------------------------------------------------------
__global__ __launch_bounds__(256) void sim_kernel(
    const _Float16* __restrict__ pa, const _Float16* __restrict__ pb,
    const float* __restrict__ W2, const float* __restrict__ b2,
    const float* __restrict__ W3, const float* __restrict__ b3,
    float* __restrict__ out)
{
    __shared__ _Float16 paLDS[32 * 32];
    const int t    = threadIdx.x;
    const int lane = t & 63;
    const int wid  = t >> 6;                       // wave in block 0..3
    const int i0 = (blockIdx.x >> 4) * 32;         // i-tile shared by block
    const int jb = (((blockIdx.x & 15) << 2) + wid) * 32;
    const int p  = lane & 31;                      // pair column within tile
    const int g  = lane >> 5;                      // k-group half (0/1)

    // stage pa i-tile: 1024 halves = 2KB, 8B per thread
    ((uint2*)paLDS)[t] = ((const uint2*)(pa + (size_t)i0 * 32))[t];

    // persistent pb fragment for this wave's 32 j's
    const _Float16* pbrow = pb + (size_t)(jb + p) * 32;
    f16x8 pblo = *(const f16x8*)(pbrow + g * 8);        // k = g*8 + e
    f16x8 pbhi = *(const f16x8*)(pbrow + 16 + g * 8);   // k = 16 + g*8 + e

    // W2 as A-operand: A[m][k], m = lane&31 (rows >= 16 zero-padded)
    f16x8 w2lo = {};
    f16x8 w2hi = {};
    if (p < 16) {
        const float* w2r = W2 + p * 32;
#pragma unroll
        for (int e = 0; e < 8; ++e) {
            w2lo[e] = (_Float16)w2r[g * 8 + e];
            w2hi[e] = (_Float16)w2r[16 + g * 8 + e];
        }
    }

    // per-lane W3 and b2(C-init) following the D row map
    float w3r[8];
    f32x16 cinit;
#pragma unroll
    for (int r = 0; r < 4; ++r) {
        w3r[r]       = W3[4 * g + r];
        w3r[4 + r]   = W3[8 + 4 * g + r];
        cinit[r]     = b2[4 * g + r];
        cinit[4 + r] = b2[8 + 4 * g + r];
    }
#pragma unroll
    for (int r = 8; r < 16; ++r) cinit[r] = 0.f;

    const float b3v = b3[0];
    const f16x8 zero = {};
    const int j = jb + p;

    __syncthreads();

#pragma unroll 4
    for (int ii = 0; ii < 32; ++ii) {
        const int i = i0 + ii;
        f16x8 alo = *(const f16x8*)&paLDS[ii * 32 + g * 8];        // broadcast
        f16x8 ahi = *(const f16x8*)&paLDS[ii * 32 + 16 + g * 8];
        f16x8 h1lo = __builtin_elementwise_max(alo + pblo, zero);  // relu(pa'+pb)
        f16x8 h1hi = __builtin_elementwise_max(ahi + pbhi, zero);

        f32x16 d = __builtin_amdgcn_mfma_f32_32x32x16_f16(w2lo, h1lo, cinit, 0, 0, 0);
        d        = __builtin_amdgcn_mfma_f32_32x32x16_f16(w2hi, h1hi, d,     0, 0, 0);

        // second layer: logit = sum_h relu(h2[h]) * W3[h] + b3
        float partial = 0.f;
#pragma unroll
        for (int r = 0; r < 8; ++r)
            partial = fmaf(fmaxf(d[r], 0.f), w3r[r], partial);
        partial += __shfl_xor(partial, 32, 64);
        const float z = partial + b3v;
        float sim = __builtin_amdgcn_rcpf(1.f + __expf(-z));
        if (i == j) sim = 1.f;
        if (lane < 32) out[(size_t)i * NN + j] = sim;
    }
}

extern "C" void kernel_launch(void* const* d_in, const int* in_sizes, int n_in,
                              void* d_out, int out_size, void* d_ws, size_t ws_size,
                              hipStream_t stream)
{
    const float* A  = (const float*)d_in[0];
    const float* Wp = (const float*)d_in[1];
    const float* bp = (const float*)d_in[2];
    const float* W1 = (const float*)d_in[3];
    const float* b1 = (const float*)d_in[4];
    const float* W2 = (const float*)d_in[5];
    const float* b2 = (const float*)d_in[6];
    const float* W3 = (const float*)d_in[7];
    const float* b3 = (const float*)d_in[8];
    float* out = (float*)d_out;

    _Float16* pa = (_Float16*)d_ws;        // 2048*32 f16 = 128 KB
    _Float16* pb = pa + NN * 32;           // next 128 KB

    prep_kernel<<<NN / 8, 256, 0, stream>>>(A, Wp, bp, W1, b1, pa, pb);
    sim_kernel<<<1024, 256, 0, stream>>>(pa, pb, W2, b2, W3, b3, out);
}